// Round 3
// baseline (4418.572 us; speedup 1.0000x reference)
//
#include <hip/hip_runtime.h>
#include <math.h>

#define D 64
#define R 5
#define BLOCK 256

__global__ __launch_bounds__(BLOCK, 4)
void bidecoder_kernel(const float* __restrict__ ufeat,
                      const float* __restrict__ ifeat,
                      const float* __restrict__ Ps,
                      const int* __restrict__ src,
                      const int* __restrict__ dst,
                      float* __restrict__ out, int E)
{
    const int e = blockIdx.x * BLOCK + threadIdx.x;
    const bool valid = (e < E);
    const int es = valid ? e : 0;                 // clamp for tail (loads harmless)

    const float* __restrict__ urow = ufeat + (size_t)src[es] * D;
    const float* __restrict__ vrow = ifeat + (size_t)dst[es] * D;

    // Full vs row register-resident: loaded from global exactly ONCE.
    float vs[D];
    #pragma unroll
    for (int q = 0; q < D / 4; ++q) {
        const float4 v4 = *reinterpret_cast<const float4*>(vrow + 4 * q);
        vs[4*q+0] = v4.x; vs[4*q+1] = v4.y; vs[4*q+2] = v4.z; vs[4*q+3] = v4.w;
    }

    float acc[R] = {0.f, 0.f, 0.f, 0.f, 0.f};

    // Main loop: only P is read (wave-uniform -> s_load into SGPRs).
    // Body per dg: 4 d's x 5 r's = 20 independent FMA chains -> full ILP.
    #pragma unroll 1
    for (int dg = 0; dg < D / 4; ++dg) {
        const float4 u4 = *reinterpret_cast<const float4*>(urow + 4 * dg);
        const float us0 = u4.x, us1 = u4.y, us2 = u4.z, us3 = u4.w;
        #pragma unroll
        for (int dd = 0; dd < 4; ++dd) {
            const int d = 4 * dg + dd;
            const float usd = (dd == 0) ? us0 : (dd == 1) ? us1 : (dd == 2) ? us2 : us3;
            #pragma unroll
            for (int r = 0; r < R; ++r) {
                const float* __restrict__ p = Ps + ((size_t)r * D + d) * D; // uniform
                float t = p[0] * vs[0];
                #pragma unroll
                for (int f = 1; f < D; ++f)
                    t = fmaf(p[f], vs[f], t);
                acc[r] = fmaf(usd, t, acc[r]);
            }
        }
    }

    // Softmax over R + expected rating.
    if (valid) {
        float m = acc[0];
        #pragma unroll
        for (int r = 1; r < R; ++r) m = fmaxf(m, acc[r]);
        float s = 0.f, num = 0.f;
        #pragma unroll
        for (int r = 0; r < R; ++r) {
            const float p = expf(acc[r] - m);
            s += p;
            num = fmaf((float)(r + 1), p, num);
        }
        out[e] = num / s;
    }
}

extern "C" void kernel_launch(void* const* d_in, const int* in_sizes, int n_in,
                              void* d_out, int out_size, void* d_ws, size_t ws_size,
                              hipStream_t stream)
{
    const float* ufeat = (const float*)d_in[0];
    const float* ifeat = (const float*)d_in[1];
    const float* Ps    = (const float*)d_in[2];
    const int*   src   = (const int*)d_in[3];
    const int*   dst   = (const int*)d_in[4];
    float*       out   = (float*)d_out;
    const int E  = in_sizes[3];
    const int nb = (E + BLOCK - 1) / BLOCK;
    hipLaunchKernelGGL(bidecoder_kernel, dim3(nb), dim3(BLOCK), 0, stream,
                       ufeat, ifeat, Ps, src, dst, out, E);
}

// Round 5
// 2098.975 us; speedup vs baseline: 2.1051x; 2.1051x over previous
//
#include <hip/hip_runtime.h>
#include <math.h>

#define D 64
#define R 5
#define BLOCK 256

// NOTE: launch_bounds minwaves MUST stay 2. With (256,4) the backend caps the
// kernel at 64 VGPRs and spills vs[64] to scratch -> 14+ GB HBM thrash (R3).
__global__ __launch_bounds__(BLOCK, 2)
void bidecoder_kernel(const float* __restrict__ ufeat,
                      const float* __restrict__ ifeat,
                      const float* __restrict__ Ps,
                      const int* __restrict__ src,
                      const int* __restrict__ dst,
                      float* __restrict__ out, int E)
{
    const int e = blockIdx.x * BLOCK + threadIdx.x;
    if (e >= E) return;                    // no barriers in kernel: early exit safe

    const float* __restrict__ urow = ufeat + (size_t)src[e] * D;
    const float* __restrict__ vrow = ifeat + (size_t)dst[e] * D;

    // Full vs row register-resident: loaded from global exactly ONCE.
    float vs[D];
    #pragma unroll
    for (int q = 0; q < D / 4; ++q) {
        const float4 v4 = *reinterpret_cast<const float4*>(vrow + 4 * q);
        vs[4*q+0] = v4.x; vs[4*q+1] = v4.y; vs[4*q+2] = v4.z; vs[4*q+3] = v4.w;
    }

    float acc[R] = {0.f, 0.f, 0.f, 0.f, 0.f};

    // Main loop: only P is read (wave-uniform -> s_load into SGPRs, scalar pipe).
    // Per dg: 4 d's x 5 r's = 20 independent FMA chains -> full FMA-pipe ILP.
    #pragma unroll 1
    for (int dg = 0; dg < D / 4; ++dg) {
        const float4 u4 = *reinterpret_cast<const float4*>(urow + 4 * dg);
        const float us0 = u4.x, us1 = u4.y, us2 = u4.z, us3 = u4.w;
        #pragma unroll
        for (int dd = 0; dd < 4; ++dd) {
            const int d = 4 * dg + dd;
            const float usd = (dd == 0) ? us0 : (dd == 1) ? us1 : (dd == 2) ? us2 : us3;
            #pragma unroll
            for (int r = 0; r < R; ++r) {
                const float* __restrict__ p = Ps + ((size_t)r * D + d) * D; // uniform
                float t = p[0] * vs[0];
                #pragma unroll
                for (int f = 1; f < D; ++f)
                    t = fmaf(p[f], vs[f], t);
                acc[r] = fmaf(usd, t, acc[r]);
            }
        }
    }

    // Softmax over R + expected rating.
    float m = acc[0];
    #pragma unroll
    for (int r = 1; r < R; ++r) m = fmaxf(m, acc[r]);
    float s = 0.f, num = 0.f;
    #pragma unroll
    for (int r = 0; r < R; ++r) {
        const float p = expf(acc[r] - m);
        s += p;
        num = fmaf((float)(r + 1), p, num);
    }
    out[e] = num / s;
}

extern "C" void kernel_launch(void* const* d_in, const int* in_sizes, int n_in,
                              void* d_out, int out_size, void* d_ws, size_t ws_size,
                              hipStream_t stream)
{
    const float* ufeat = (const float*)d_in[0];
    const float* ifeat = (const float*)d_in[1];
    const float* Ps    = (const float*)d_in[2];
    const int*   src   = (const int*)d_in[3];
    const int*   dst   = (const int*)d_in[4];
    float*       out   = (float*)d_out;
    const int E  = in_sizes[3];
    const int nb = (E + BLOCK - 1) / BLOCK;
    hipLaunchKernelGGL(bidecoder_kernel, dim3(nb), dim3(BLOCK), 0, stream,
                       ufeat, ifeat, Ps, src, dst, out, E);
}